// Round 1
// baseline (455.155 us; speedup 1.0000x reference)
//
#include <hip/hip_runtime.h>
#include <stdint.h>
#include <math.h>

#define NB 4
#define NN 4096
#define NF 256
#define ND 128

typedef __bf16 bf16x8 __attribute__((ext_vector_type(8)));
typedef float f32x4 __attribute__((ext_vector_type(4)));
typedef unsigned short u16x8 __attribute__((ext_vector_type(8)));
typedef unsigned short u16x4 __attribute__((ext_vector_type(4)));
typedef int i32x4 __attribute__((ext_vector_type(4)));

__device__ __forceinline__ unsigned short f2bf(float f) {
    union { float f; uint32_t u; } v; v.f = f;
    uint32_t r = (v.u + 0x7FFFu + ((v.u >> 16) & 1u)) >> 16;
    return (unsigned short)r;
}

__device__ __forceinline__ bf16x8 lds_read16(const unsigned short* base, int byte_off) {
    return *reinterpret_cast<const bf16x8*>(reinterpret_cast<const char*>(base) + byte_off);
}

// ---------------- Kernel 1: QKV projection (bf16 MFMA, f32 acc) ----------------
// grid (256, 3): x = 64-row tile of B*N, y = which projection (0=Q,1=K,2=V)
// Q is pre-scaled by 1/sqrt(128).
__global__ __launch_bounds__(256) void qkv_proj(
    const float* __restrict__ h,
    const float* __restrict__ Wq, const float* __restrict__ bq,
    const float* __restrict__ Wk, const float* __restrict__ bk,
    const float* __restrict__ Wv, const float* __restrict__ bv,
    unsigned short* __restrict__ qo, unsigned short* __restrict__ ko,
    unsigned short* __restrict__ vo, float qscale)
{
    __shared__ unsigned short h_lds[64 * 128];   // [64 rows][128 k] bf16, swizzled
    __shared__ unsigned short w_lds[128 * 128];  // [128 d][128 k] bf16, swizzled

    const int tid = threadIdx.x;
    const int lane = tid & 63;
    const int wv = tid >> 6;
    const int l15 = lane & 15;
    const int lhi = lane >> 4;
    const int R0 = blockIdx.x * 64;
    const int proj = blockIdx.y;

    const float* W    = proj == 0 ? Wq : (proj == 1 ? Wk : Wv);
    const float* bias = proj == 0 ? bq : (proj == 1 ? bk : bv);
    unsigned short* out = proj == 0 ? qo : (proj == 1 ? ko : vo);
    const float scale = proj == 0 ? qscale : 1.0f;

    f32x4 acc[8];
#pragma unroll
    for (int i = 0; i < 8; ++i) acc[i] = f32x4{0.f, 0.f, 0.f, 0.f};

    for (int kc = 0; kc < 2; ++kc) {
        const int c0 = kc * 128;
        __syncthreads();
        // stage h tile 64x128 (f32 -> bf16)
#pragma unroll
        for (int p = 0; p < 8; ++p) {
            int idx = p * 256 + tid;
            int row = idx >> 5;
            int seg = idx & 31;
            f32x4 hv = *reinterpret_cast<const f32x4*>(h + (size_t)(R0 + row) * NF + c0 + seg * 4);
            u16x4 hb;
            hb[0] = f2bf(hv[0]); hb[1] = f2bf(hv[1]); hb[2] = f2bf(hv[2]); hb[3] = f2bf(hv[3]);
            int byte = (row * 256 + seg * 8) ^ ((row & 7) << 4);
            *reinterpret_cast<u16x4*>(reinterpret_cast<char*>(h_lds) + byte) = hb;
        }
        // stage W tile 128x128 (f32 -> bf16)
#pragma unroll
        for (int p = 0; p < 16; ++p) {
            int idx = p * 256 + tid;
            int row = idx >> 5;
            int seg = idx & 31;
            f32x4 wv4 = *reinterpret_cast<const f32x4*>(W + (size_t)row * NF + c0 + seg * 4);
            u16x4 wb;
            wb[0] = f2bf(wv4[0]); wb[1] = f2bf(wv4[1]); wb[2] = f2bf(wv4[2]); wb[3] = f2bf(wv4[3]);
            int byte = (row * 256 + seg * 8) ^ ((row & 7) << 4);
            *reinterpret_cast<u16x4*>(reinterpret_cast<char*>(w_lds) + byte) = wb;
        }
        __syncthreads();
        const int arow = 16 * wv + l15;
#pragma unroll
        for (int ks = 0; ks < 4; ++ks) {
            int k = ks * 32 + 8 * lhi;
            bf16x8 a = lds_read16(h_lds, (arow * 256 + k * 2) ^ ((arow & 7) << 4));
#pragma unroll
            for (int cs = 0; cs < 8; ++cs) {
                int d = 16 * cs + l15;
                bf16x8 b = lds_read16(w_lds, (d * 256 + k * 2) ^ ((d & 7) << 4));
                acc[cs] = __builtin_amdgcn_mfma_f32_16x16x32_bf16(a, b, acc[cs], 0, 0, 0);
            }
        }
    }
    // epilogue: bias, scale, bf16 store
#pragma unroll
    for (int cs = 0; cs < 8; ++cs) {
        int d = 16 * cs + l15;
        float bb = bias[d];
#pragma unroll
        for (int j = 0; j < 4; ++j) {
            int row = R0 + 16 * wv + 4 * lhi + j;
            float val = (acc[cs][j] + bb) * scale;
            out[(size_t)row * ND + d] = f2bf(val);
        }
    }
}

// ---------------- Kernel 2: fused masked flash attention ----------------
// grid (64, 4): x = 64-row Q tile, y = batch. 4 waves, wave w owns rows 16w..16w+15.
__global__ __launch_bounds__(256) void attn(
    const unsigned short* __restrict__ Q,   // [B*N,128] bf16, pre-scaled
    const unsigned short* __restrict__ K,   // [B*N,128] bf16
    const unsigned short* __restrict__ V,   // [B*N,128] bf16
    const int* __restrict__ adj,            // [B,N,N] i32
    float* __restrict__ out)                // [B*N,128] f32
{
    __shared__ unsigned short k_lds[64 * 128];   // [64 m][128 d] swizzled
    __shared__ unsigned short vt_lds[128 * 64];  // [128 d][64 m] swizzled (V^T)
    __shared__ int aq_lds[64 * 64];              // adj tile (col-XOR); also Q staging
    __shared__ unsigned short p_lds[4 * 16 * 64]; // per-wave P tile, swizzled

    const int tid = threadIdx.x;
    const int lane = tid & 63;
    const int wv = tid >> 6;
    const int l15 = lane & 15;
    const int lhi = lane >> 4;
    const int b = blockIdx.y;
    const int q0 = blockIdx.x * 64;
    const size_t bN = (size_t)b * NN;

    // ---- stage Q tile into aq_lds (reused), load A-fragments
    unsigned short* q_st = reinterpret_cast<unsigned short*>(aq_lds);
#pragma unroll
    for (int p = 0; p < 4; ++p) {
        int idx = p * 256 + tid;
        int row = idx >> 4;
        int seg = idx & 15;
        u16x8 qv = *reinterpret_cast<const u16x8*>(Q + (bN + q0 + row) * ND + seg * 8);
        int byte = (row * 256 + seg * 16) ^ ((row & 7) << 4);
        *reinterpret_cast<u16x8*>(reinterpret_cast<char*>(q_st) + byte) = qv;
    }
    __syncthreads();
    bf16x8 qfrag[4];
    {
        const int arow = 16 * wv + l15;
#pragma unroll
        for (int ks = 0; ks < 4; ++ks) {
            int k = ks * 32 + 8 * lhi;
            qfrag[ks] = lds_read16(q_st, (arow * 256 + k * 2) ^ ((arow & 7) << 4));
        }
    }

    f32x4 acc_o[8];
#pragma unroll
    for (int i = 0; i < 8; ++i) acc_o[i] = f32x4{0.f, 0.f, 0.f, 0.f};
    float m_run[4], l_run[4];
#pragma unroll
    for (int j = 0; j < 4; ++j) { m_run[j] = -INFINITY; l_run[j] = 0.f; }

    for (int mt = 0; mt < NN / 64; ++mt) {
        const int m0 = mt * 64;
        __syncthreads();  // previous iteration's reads done before overwrite
        // ---- stage K tile [64][128]
#pragma unroll
        for (int p = 0; p < 4; ++p) {
            int idx = p * 256 + tid;
            int row = idx >> 4;
            int seg = idx & 15;
            u16x8 kv = *reinterpret_cast<const u16x8*>(K + (bN + m0 + row) * ND + seg * 8);
            int byte = (row * 256 + seg * 16) ^ ((row & 7) << 4);
            *reinterpret_cast<u16x8*>(reinterpret_cast<char*>(k_lds) + byte) = kv;
        }
        // ---- stage V tile transposed -> vt_lds[d][m]
#pragma unroll
        for (int p = 0; p < 4; ++p) {
            int idx = p * 256 + tid;
            int m = idx >> 4;
            int seg = idx & 15;
            u16x8 vv = *reinterpret_cast<const u16x8*>(V + (bN + m0 + m) * ND + seg * 8);
            int d0 = seg * 8;
#pragma unroll
            for (int j = 0; j < 8; ++j) {
                int d = d0 + j;
                int byte = (d * 128 + m * 2) ^ ((d & 7) << 4);
                *reinterpret_cast<unsigned short*>(reinterpret_cast<char*>(vt_lds) + byte) = vv[j];
            }
        }
        // ---- stage adj tile [64 q][64 m] with col-XOR anti-conflict
#pragma unroll
        for (int p = 0; p < 4; ++p) {
            int idx = p * 256 + tid;
            int row = idx >> 4;
            int seg = idx & 15;
            i32x4 av = *reinterpret_cast<const i32x4*>(adj + (bN + q0 + row) * NN + m0 + seg * 4);
            int col = (seg * 4) ^ (((row >> 2) & 3) << 2);
            *reinterpret_cast<i32x4*>(&aq_lds[row * 64 + col]) = av;
        }
        __syncthreads();

        // ---- S = Q K^T  (f32x4 per 16x16 tile, 4 m-subtiles)
        f32x4 s[4];
#pragma unroll
        for (int ms = 0; ms < 4; ++ms) {
            s[ms] = f32x4{0.f, 0.f, 0.f, 0.f};
#pragma unroll
            for (int ks = 0; ks < 4; ++ks) {
                int mrow = 16 * ms + l15;
                int k = ks * 32 + 8 * lhi;
                bf16x8 bfrag = lds_read16(k_lds, (mrow * 256 + k * 2) ^ ((mrow & 7) << 4));
                s[ms] = __builtin_amdgcn_mfma_f32_16x16x32_bf16(qfrag[ks], bfrag, s[ms], 0, 0, 0);
            }
        }
        // ---- mask (scale already folded into Q)
#pragma unroll
        for (int ms = 0; ms < 4; ++ms) {
#pragma unroll
            for (int j = 0; j < 4; ++j) {
                int r = 16 * wv + 4 * lhi + j;
                int c = 16 * ms + l15;
                int a = aq_lds[r * 64 + (c ^ (lhi << 2))];
                if (a == 0) s[ms][j] = -9e15f;
            }
        }
        // ---- online softmax
        float mnew[4], corr[4];
#pragma unroll
        for (int j = 0; j < 4; ++j) {
            float mx = fmaxf(fmaxf(s[0][j], s[1][j]), fmaxf(s[2][j], s[3][j]));
#pragma unroll
            for (int off = 1; off < 16; off <<= 1)
                mx = fmaxf(mx, __shfl_xor(mx, off, 64));
            mnew[j] = fmaxf(m_run[j], mx);
            corr[j] = __expf(m_run[j] - mnew[j]);
            m_run[j] = mnew[j];
        }
        float rsum[4] = {0.f, 0.f, 0.f, 0.f};
        unsigned short pb[4][4];
#pragma unroll
        for (int ms = 0; ms < 4; ++ms) {
#pragma unroll
            for (int j = 0; j < 4; ++j) {
                float p = __expf(s[ms][j] - mnew[j]);
                rsum[j] += p;
                pb[ms][j] = f2bf(p);
            }
        }
#pragma unroll
        for (int j = 0; j < 4; ++j) {
            float rs = rsum[j];
#pragma unroll
            for (int off = 1; off < 16; off <<= 1)
                rs += __shfl_xor(rs, off, 64);
            l_run[j] = l_run[j] * corr[j] + rs;
#pragma unroll
            for (int ds = 0; ds < 8; ++ds) acc_o[ds][j] *= corr[j];
        }
        // ---- write P (bf16) to per-wave LDS tile, swizzled
#pragma unroll
        for (int ms = 0; ms < 4; ++ms) {
#pragma unroll
            for (int j = 0; j < 4; ++j) {
                int r = 4 * lhi + j;
                int c = 16 * ms + l15;
                int byte = (wv * 2048 + r * 128 + c * 2) ^ ((r & 7) << 4);
                *reinterpret_cast<unsigned short*>(reinterpret_cast<char*>(p_lds) + byte) = pb[ms][j];
            }
        }
        // same-wave LDS RAW: compiler orders via lgkmcnt (no barrier needed)
        // ---- PV: acc_o += P @ V
#pragma unroll
        for (int ks2 = 0; ks2 < 2; ++ks2) {
            int mloc = ks2 * 32 + 8 * lhi;
            bf16x8 pa = lds_read16(p_lds, (wv * 2048 + l15 * 128 + mloc * 2) ^ ((l15 & 7) << 4));
#pragma unroll
            for (int ds = 0; ds < 8; ++ds) {
                int d = 16 * ds + l15;
                bf16x8 vb = lds_read16(vt_lds, (d * 128 + mloc * 2) ^ ((d & 7) << 4));
                acc_o[ds] = __builtin_amdgcn_mfma_f32_16x16x32_bf16(pa, vb, acc_o[ds], 0, 0, 0);
            }
        }
    }

    // ---- epilogue: normalize and store f32
    float inv[4];
#pragma unroll
    for (int j = 0; j < 4; ++j) inv[j] = 1.0f / l_run[j];
#pragma unroll
    for (int ds = 0; ds < 8; ++ds) {
        int d = 16 * ds + l15;
#pragma unroll
        for (int j = 0; j < 4; ++j) {
            int row = q0 + 16 * wv + 4 * lhi + j;
            out[(bN + row) * ND + d] = acc_o[ds][j] * inv[j];
        }
    }
}

extern "C" void kernel_launch(void* const* d_in, const int* in_sizes, int n_in,
                              void* d_out, int out_size, void* d_ws, size_t ws_size,
                              hipStream_t stream) {
    const float* h  = (const float*)d_in[0];
    const int* adj  = (const int*)d_in[1];
    const float* Wq = (const float*)d_in[2];
    const float* bq = (const float*)d_in[3];
    const float* Wk = (const float*)d_in[4];
    const float* bk = (const float*)d_in[5];
    const float* Wv = (const float*)d_in[6];
    const float* bv = (const float*)d_in[7];
    float* out = (float*)d_out;

    unsigned short* qws = (unsigned short*)d_ws;
    unsigned short* kws = qws + (size_t)NB * NN * ND;
    unsigned short* vws = kws + (size_t)NB * NN * ND;

    const float qscale = 0.08838834764831845f;  // 1/sqrt(128)

    qkv_proj<<<dim3(NB * NN / 64, 3), 256, 0, stream>>>(
        h, Wq, bq, Wk, bk, Wv, bv, qws, kws, vws, qscale);
    attn<<<dim3(NN / 64, NB), 256, 0, stream>>>(qws, kws, vws, adj, out);
}

// Round 2
// 219.266 us; speedup vs baseline: 2.0758x; 2.0758x over previous
//
#include <hip/hip_runtime.h>
#include <stdint.h>
#include <math.h>

#define NB 4
#define NN 4096
#define NF 256
#define ND 128
#define QB 32            // q rows per attn block
#define KVB 64           // kv rows per tile
#define NT (NN / KVB)    // 64 tiles

typedef __bf16 bf16x8 __attribute__((ext_vector_type(8)));
typedef float f32x4 __attribute__((ext_vector_type(4)));
typedef unsigned short u16x8 __attribute__((ext_vector_type(8)));
typedef unsigned short u16x4 __attribute__((ext_vector_type(4)));

__device__ __forceinline__ unsigned short f2bf(float f) {
    union { float f; uint32_t u; } v; v.f = f;
    uint32_t r = (v.u + 0x7FFFu + ((v.u >> 16) & 1u)) >> 16;
    return (unsigned short)r;
}

__device__ __forceinline__ bf16x8 lds_read16(const unsigned short* base, int byte_off) {
    return *reinterpret_cast<const bf16x8*>(reinterpret_cast<const char*>(base) + byte_off);
}

__device__ __forceinline__ void gld_lds16(const void* g, void* l) {
    __builtin_amdgcn_global_load_lds(
        (const __attribute__((address_space(1))) void*)g,
        (__attribute__((address_space(3))) void*)l, 16, 0, 0);
}

// ---------------- Kernel 1: QKV projection (bf16 MFMA, f32 acc) ----------------
// grid (256, 3): x = 64-row tile of B*N, y = projection (0=Q,1=K,2=V).
// Q pre-scaled by 1/sqrt(128). V written TRANSPOSED: vt[b][d][n].
__global__ __launch_bounds__(256) void qkv_proj(
    const float* __restrict__ h,
    const float* __restrict__ Wq, const float* __restrict__ bq,
    const float* __restrict__ Wk, const float* __restrict__ bk,
    const float* __restrict__ Wv, const float* __restrict__ bv,
    unsigned short* __restrict__ qo, unsigned short* __restrict__ ko,
    unsigned short* __restrict__ vt, float qscale)
{
    __shared__ unsigned short h_lds[64 * 128];
    __shared__ unsigned short w_lds[128 * 128];

    const int tid = threadIdx.x;
    const int lane = tid & 63;
    const int wv = tid >> 6;
    const int l15 = lane & 15;
    const int lhi = lane >> 4;
    const int R0 = blockIdx.x * 64;
    const int proj = blockIdx.y;

    const float* W    = proj == 0 ? Wq : (proj == 1 ? Wk : Wv);
    const float* bias = proj == 0 ? bq : (proj == 1 ? bk : bv);
    const float scale = proj == 0 ? qscale : 1.0f;

    f32x4 acc[8];
#pragma unroll
    for (int i = 0; i < 8; ++i) acc[i] = f32x4{0.f, 0.f, 0.f, 0.f};

    for (int kc = 0; kc < 2; ++kc) {
        const int c0 = kc * 128;
        __syncthreads();
#pragma unroll
        for (int p = 0; p < 8; ++p) {
            int idx = p * 256 + tid;
            int row = idx >> 5;
            int seg = idx & 31;
            f32x4 hv = *reinterpret_cast<const f32x4*>(h + (size_t)(R0 + row) * NF + c0 + seg * 4);
            u16x4 hb;
            hb[0] = f2bf(hv[0]); hb[1] = f2bf(hv[1]); hb[2] = f2bf(hv[2]); hb[3] = f2bf(hv[3]);
            int byte = (row * 256 + seg * 8) ^ ((row & 7) << 4);
            *reinterpret_cast<u16x4*>(reinterpret_cast<char*>(h_lds) + byte) = hb;
        }
#pragma unroll
        for (int p = 0; p < 16; ++p) {
            int idx = p * 256 + tid;
            int row = idx >> 5;
            int seg = idx & 31;
            f32x4 wv4 = *reinterpret_cast<const f32x4*>(W + (size_t)row * NF + c0 + seg * 4);
            u16x4 wb;
            wb[0] = f2bf(wv4[0]); wb[1] = f2bf(wv4[1]); wb[2] = f2bf(wv4[2]); wb[3] = f2bf(wv4[3]);
            int byte = (row * 256 + seg * 8) ^ ((row & 7) << 4);
            *reinterpret_cast<u16x4*>(reinterpret_cast<char*>(w_lds) + byte) = wb;
        }
        __syncthreads();
        const int arow = 16 * wv + l15;
#pragma unroll
        for (int ks = 0; ks < 4; ++ks) {
            int k = ks * 32 + 8 * lhi;
            bf16x8 a = lds_read16(h_lds, (arow * 256 + k * 2) ^ ((arow & 7) << 4));
#pragma unroll
            for (int cs = 0; cs < 8; ++cs) {
                int d = 16 * cs + l15;
                bf16x8 b = lds_read16(w_lds, (d * 256 + k * 2) ^ ((d & 7) << 4));
                acc[cs] = __builtin_amdgcn_mfma_f32_16x16x32_bf16(a, b, acc[cs], 0, 0, 0);
            }
        }
    }
    if (proj < 2) {
        unsigned short* out = proj == 0 ? qo : ko;
#pragma unroll
        for (int cs = 0; cs < 8; ++cs) {
            int d = 16 * cs + l15;
            float bb = bias[d];
#pragma unroll
            for (int j = 0; j < 4; ++j) {
                int row = R0 + 16 * wv + 4 * lhi + j;
                out[(size_t)row * ND + d] = f2bf((acc[cs][j] + bb) * scale);
            }
        }
    } else {
        // V transposed: vt[b][d][n]
        const int bb_ = R0 >> 12;
        const int n0 = (R0 & (NN - 1)) + 16 * wv + 4 * lhi;
#pragma unroll
        for (int cs = 0; cs < 8; ++cs) {
            int d = 16 * cs + l15;
            float bb = bias[d];
            u16x4 o;
#pragma unroll
            for (int j = 0; j < 4; ++j) o[j] = f2bf(acc[cs][j] + bb);
            *reinterpret_cast<u16x4*>(vt + ((size_t)bb_ * ND + d) * NN + n0) = o;
        }
    }
}

// ---------------- Kernel 2: fused masked flash attention ----------------
// grid 512 blocks x 128 threads: 2 waves, wave w owns q rows 16w..16w+15.
// Double-buffered async pipeline: global_load_lds for K/V^T (pre-swizzled
// source), adj in registers, counted vmcnt, raw barriers.
__global__ __launch_bounds__(128) void attn(
    const unsigned short* __restrict__ Q,   // [B*N,128] bf16, pre-scaled
    const unsigned short* __restrict__ K,   // [B*N,128] bf16
    const unsigned short* __restrict__ VT,  // [B][128][N] bf16
    const int* __restrict__ adj,            // [B,N,N] i32
    float* __restrict__ out)                // [B*N,128] f32
{
    __shared__ unsigned short kA[KVB * 128], kB[KVB * 128];   // 16 KB each
    __shared__ unsigned short vA[128 * KVB], vB[128 * KVB];   // 16 KB each
    __shared__ unsigned short p_lds[2 * 16 * 64];             // per-wave P tile

    const int tid = threadIdx.x;
    const int lane = tid & 63;
    const int w = tid >> 6;        // 0..1
    const int l15 = lane & 15;
    const int lhi = lane >> 4;

    // bijective XCD swizzle: 512 wgs, 64 per XCD -> each XCD gets 64
    // consecutive q-tiles of one batch (K/V^T of that batch fits its L2)
    int flat = blockIdx.x + gridDim.x * blockIdx.y;
    int swz = (flat & 7) * 64 + (flat >> 3);
    const int qt = swz & 127;
    const int b = swz >> 7;
    const int q0 = qt * QB;
    const size_t bN = (size_t)b * NN;
    const size_t abase = (size_t)b * NN * NN;

    // ---- async stage K + V^T tile into LDS (linear dest, pre-swizzled source)
    auto stage = [&](unsigned short* kb, unsigned short* vb, int tile) {
        const int m0 = tile * KVB;
#pragma unroll
        for (int i = 0; i < 8; ++i) {
            int slot = w * 8 + i;                       // 1 KB slots
            int row = slot * 4 + (lane >> 4);           // K row (m)
            int pc = lane & 15;                         // physical 16B chunk
            int lc = pc ^ (row & 7);                    // logical chunk
            gld_lds16(K + (bN + m0 + row) * ND + lc * 8, kb + slot * 512);
        }
#pragma unroll
        for (int i = 0; i < 8; ++i) {
            int slot = w * 8 + i;
            int d = slot * 8 + (lane >> 3);             // V^T row (d)
            int pc = lane & 7;
            int lc = pc ^ (d & 7);
            gld_lds16(VT + ((size_t)b * ND + d) * NN + m0 + lc * 8, vb + slot * 512);
        }
    };
    // ---- adj tile -> 16 registers (coalesced 64B segments per instr)
    auto adj_load = [&](int (&ar)[16], int tile) {
        const int m0 = tile * KVB;
#pragma unroll
        for (int ms = 0; ms < 4; ++ms)
#pragma unroll
            for (int j = 0; j < 4; ++j) {
                int r = 16 * w + 4 * lhi + j;
                int c = 16 * ms + l15;
                ar[ms * 4 + j] = adj[abase + (size_t)(q0 + r) * NN + m0 + c];
            }
    };

    int aregA[16], aregB[16];
    stage(kA, vA, 0);
    adj_load(aregA, 0);

    // Q fragments straight from global (no LDS)
    bf16x8 qf[4];
#pragma unroll
    for (int ks = 0; ks < 4; ++ks)
        qf[ks] = *reinterpret_cast<const bf16x8*>(Q + (bN + q0 + 16 * w + l15) * ND + ks * 32 + 8 * lhi);

    f32x4 acc_o[8];
#pragma unroll
    for (int i = 0; i < 8; ++i) acc_o[i] = f32x4{0.f, 0.f, 0.f, 0.f};
    float m_run[4], l_run[4];
#pragma unroll
    for (int j = 0; j < 4; ++j) { m_run[j] = -INFINITY; l_run[j] = 0.f; }

    auto body = [&](unsigned short* kcur, unsigned short* vcur, const int (&acur)[16],
                    unsigned short* knxt, unsigned short* vnxt, int (&anxt)[16], int t) {
        int tn = (t + 1 < NT) ? t + 1 : NT - 1;   // clamp: re-stage last tile (L2-hot)
        stage(knxt, vnxt, tn);
        adj_load(anxt, tn);
        // wait for CURRENT tile (issued last iter); 32 youngest stay in flight
        asm volatile("s_waitcnt vmcnt(32)" ::: "memory");
        __builtin_amdgcn_s_barrier();
        __builtin_amdgcn_sched_barrier(0);

        // ---- S = Q K^T
        f32x4 s[4];
#pragma unroll
        for (int ms = 0; ms < 4; ++ms) {
            s[ms] = f32x4{0.f, 0.f, 0.f, 0.f};
#pragma unroll
            for (int ks = 0; ks < 4; ++ks) {
                int mrow = 16 * ms + l15;
                bf16x8 bf = lds_read16(kcur, (mrow * 256 + ks * 64 + lhi * 16) ^ ((mrow & 7) << 4));
                s[ms] = __builtin_amdgcn_mfma_f32_16x16x32_bf16(qf[ks], bf, s[ms], 0, 0, 0);
            }
        }
        // ---- mask
#pragma unroll
        for (int ms = 0; ms < 4; ++ms)
#pragma unroll
            for (int j = 0; j < 4; ++j)
                if (acur[ms * 4 + j] == 0) s[ms][j] = -9e15f;
        // ---- online softmax
        float mnew[4], corr[4];
#pragma unroll
        for (int j = 0; j < 4; ++j) {
            float mx = fmaxf(fmaxf(s[0][j], s[1][j]), fmaxf(s[2][j], s[3][j]));
#pragma unroll
            for (int off = 1; off < 16; off <<= 1)
                mx = fmaxf(mx, __shfl_xor(mx, off, 64));
            mnew[j] = fmaxf(m_run[j], mx);
            corr[j] = __expf(m_run[j] - mnew[j]);
            m_run[j] = mnew[j];
        }
        float rsum[4] = {0.f, 0.f, 0.f, 0.f};
        unsigned short pb[4][4];
#pragma unroll
        for (int ms = 0; ms < 4; ++ms)
#pragma unroll
            for (int j = 0; j < 4; ++j) {
                float p = __expf(s[ms][j] - mnew[j]);
                rsum[j] += p;
                pb[ms][j] = f2bf(p);
            }
#pragma unroll
        for (int j = 0; j < 4; ++j) {
            float rs = rsum[j];
#pragma unroll
            for (int off = 1; off < 16; off <<= 1)
                rs += __shfl_xor(rs, off, 64);
            l_run[j] = l_run[j] * corr[j] + rs;
#pragma unroll
            for (int ds = 0; ds < 8; ++ds) acc_o[ds][j] *= corr[j];
        }
        // ---- P -> per-wave LDS (swizzled); same-wave RAW ordered by lgkmcnt
#pragma unroll
        for (int ms = 0; ms < 4; ++ms)
#pragma unroll
            for (int j = 0; j < 4; ++j) {
                int r = 4 * lhi + j;
                int c = 16 * ms + l15;
                int byte = (w * 2048 + r * 128 + c * 2) ^ ((r & 7) << 4);
                *reinterpret_cast<unsigned short*>(reinterpret_cast<char*>(p_lds) + byte) = pb[ms][j];
            }
        // ---- PV: acc_o += P @ V
#pragma unroll
        for (int ks2 = 0; ks2 < 2; ++ks2) {
            int mloc = ks2 * 32 + 8 * lhi;
            bf16x8 pa = lds_read16(p_lds, (w * 2048 + l15 * 128 + mloc * 2) ^ ((l15 & 7) << 4));
#pragma unroll
            for (int ds = 0; ds < 8; ++ds) {
                int d = 16 * ds + l15;
                bf16x8 vbf = lds_read16(vcur, (d * 128 + mloc * 2) ^ ((d & 7) << 4));
                acc_o[ds] = __builtin_amdgcn_mfma_f32_16x16x32_bf16(pa, vbf, acc_o[ds], 0, 0, 0);
            }
        }
        asm volatile("s_waitcnt lgkmcnt(0)" ::: "memory");
        __builtin_amdgcn_sched_barrier(0);
        __builtin_amdgcn_s_barrier();
        __builtin_amdgcn_sched_barrier(0);
    };

    for (int t = 0; t < NT; t += 2) {
        body(kA, vA, aregA, kB, vB, aregB, t);
        body(kB, vB, aregB, kA, vA, aregA, t + 1);
    }

    // ---- epilogue
    float inv[4];
#pragma unroll
    for (int j = 0; j < 4; ++j) inv[j] = 1.0f / l_run[j];
#pragma unroll
    for (int ds = 0; ds < 8; ++ds) {
        int d = 16 * ds + l15;
#pragma unroll
        for (int j = 0; j < 4; ++j) {
            int row = q0 + 16 * w + 4 * lhi + j;
            out[(bN + row) * ND + d] = acc_o[ds][j] * inv[j];
        }
    }
}

extern "C" void kernel_launch(void* const* d_in, const int* in_sizes, int n_in,
                              void* d_out, int out_size, void* d_ws, size_t ws_size,
                              hipStream_t stream) {
    const float* h  = (const float*)d_in[0];
    const int* adj  = (const int*)d_in[1];
    const float* Wq = (const float*)d_in[2];
    const float* bq = (const float*)d_in[3];
    const float* Wk = (const float*)d_in[4];
    const float* bk = (const float*)d_in[5];
    const float* Wv = (const float*)d_in[6];
    const float* bv = (const float*)d_in[7];
    float* out = (float*)d_out;

    unsigned short* qws = (unsigned short*)d_ws;
    unsigned short* kws = qws + (size_t)NB * NN * ND;
    unsigned short* vtws = kws + (size_t)NB * NN * ND;

    const float qscale = 0.08838834764831845f;  // 1/sqrt(128)

    qkv_proj<<<dim3(NB * NN / 64, 3), 256, 0, stream>>>(
        h, Wq, bq, Wk, bk, Wv, bv, qws, kws, vtws, qscale);
    attn<<<dim3(128, NB), 128, 0, stream>>>(qws, kws, vtws, adj, out);
}

// Round 3
// 171.559 us; speedup vs baseline: 2.6531x; 1.2781x over previous
//
#include <hip/hip_runtime.h>
#include <stdint.h>
#include <math.h>

#define NB 4
#define NN 4096
#define NF 256
#define ND 128
#define QB 32            // q rows per attn block
#define KVB 32           // kv rows per tile
#define NSPLIT 2
#define NTL (NN / KVB / NSPLIT)   // 64 logical tiles per split
#define NR (NB * NN)

typedef __bf16 bf16x8 __attribute__((ext_vector_type(8)));
typedef float f32x4 __attribute__((ext_vector_type(4)));
typedef unsigned short u16x8 __attribute__((ext_vector_type(8)));
typedef unsigned short u16x4 __attribute__((ext_vector_type(4)));

__device__ __forceinline__ unsigned short f2bf(float f) {
    union { float f; uint32_t u; } v; v.f = f;
    uint32_t r = (v.u + 0x7FFFu + ((v.u >> 16) & 1u)) >> 16;
    return (unsigned short)r;
}

__device__ __forceinline__ bf16x8 lds_read16(const unsigned short* base, int byte_off) {
    return *reinterpret_cast<const bf16x8*>(reinterpret_cast<const char*>(base) + byte_off);
}

__device__ __forceinline__ void gld_lds16(const void* g, void* l) {
    __builtin_amdgcn_global_load_lds(
        (const __attribute__((address_space(1))) void*)g,
        (__attribute__((address_space(3))) void*)l, 16, 0, 0);
}

// ---------------- Kernel 1: QKV projection (bf16 MFMA, f32 acc) ----------------
// grid (256, 3): x = 64-row tile of B*N, y = projection (0=Q,1=K,2=V).
// Q pre-scaled by 1/sqrt(128). V written in attn-LDS tile order:
//   VS[b][tile(128)][chunk(4)][d(128)][m8] bf16  (tile=32 m-rows, chunk=8 m's)
__global__ __launch_bounds__(256) void qkv_proj(
    const float* __restrict__ h,
    const float* __restrict__ Wq, const float* __restrict__ bq,
    const float* __restrict__ Wk, const float* __restrict__ bk,
    const float* __restrict__ Wv, const float* __restrict__ bv,
    unsigned short* __restrict__ qo, unsigned short* __restrict__ ko,
    unsigned short* __restrict__ vs, float qscale)
{
    __shared__ unsigned short h_lds[64 * 128];
    __shared__ unsigned short w_lds[128 * 128];

    const int tid = threadIdx.x;
    const int lane = tid & 63;
    const int wv = tid >> 6;
    const int l15 = lane & 15;
    const int lhi = lane >> 4;
    const int R0 = blockIdx.x * 64;
    const int proj = blockIdx.y;

    const float* W    = proj == 0 ? Wq : (proj == 1 ? Wk : Wv);
    const float* bias = proj == 0 ? bq : (proj == 1 ? bk : bv);
    const float scale = proj == 0 ? qscale : 1.0f;

    f32x4 acc[8];
#pragma unroll
    for (int i = 0; i < 8; ++i) acc[i] = f32x4{0.f, 0.f, 0.f, 0.f};

    for (int kc = 0; kc < 2; ++kc) {
        const int c0 = kc * 128;
        __syncthreads();
#pragma unroll
        for (int p = 0; p < 8; ++p) {
            int idx = p * 256 + tid;
            int row = idx >> 5;
            int seg = idx & 31;
            f32x4 hv = *reinterpret_cast<const f32x4*>(h + (size_t)(R0 + row) * NF + c0 + seg * 4);
            u16x4 hb;
            hb[0] = f2bf(hv[0]); hb[1] = f2bf(hv[1]); hb[2] = f2bf(hv[2]); hb[3] = f2bf(hv[3]);
            int byte = (row * 256 + seg * 8) ^ ((row & 7) << 4);
            *reinterpret_cast<u16x4*>(reinterpret_cast<char*>(h_lds) + byte) = hb;
        }
#pragma unroll
        for (int p = 0; p < 16; ++p) {
            int idx = p * 256 + tid;
            int row = idx >> 5;
            int seg = idx & 31;
            f32x4 wv4 = *reinterpret_cast<const f32x4*>(W + (size_t)row * NF + c0 + seg * 4);
            u16x4 wb;
            wb[0] = f2bf(wv4[0]); wb[1] = f2bf(wv4[1]); wb[2] = f2bf(wv4[2]); wb[3] = f2bf(wv4[3]);
            int byte = (row * 256 + seg * 8) ^ ((row & 7) << 4);
            *reinterpret_cast<u16x4*>(reinterpret_cast<char*>(w_lds) + byte) = wb;
        }
        __syncthreads();
        const int arow = 16 * wv + l15;
#pragma unroll
        for (int ks = 0; ks < 4; ++ks) {
            int k = ks * 32 + 8 * lhi;
            bf16x8 a = lds_read16(h_lds, (arow * 256 + k * 2) ^ ((arow & 7) << 4));
#pragma unroll
            for (int cs = 0; cs < 8; ++cs) {
                int d = 16 * cs + l15;
                bf16x8 b = lds_read16(w_lds, (d * 256 + k * 2) ^ ((d & 7) << 4));
                acc[cs] = __builtin_amdgcn_mfma_f32_16x16x32_bf16(a, b, acc[cs], 0, 0, 0);
            }
        }
    }
    if (proj < 2) {
        unsigned short* out = proj == 0 ? qo : ko;
#pragma unroll
        for (int cs = 0; cs < 8; ++cs) {
            int d = 16 * cs + l15;
            float bb = bias[d];
#pragma unroll
            for (int j = 0; j < 4; ++j) {
                int row = R0 + 16 * wv + 4 * lhi + j;
                out[(size_t)row * ND + d] = f2bf((acc[cs][j] + bb) * scale);
            }
        }
    } else {
        // V in attn-tile layout
        const int bb_ = R0 >> 12;
        const int nb_ = (R0 & (NN - 1)) + 16 * wv + 4 * lhi;   // first of 4 consecutive n
        const int pt = nb_ >> 5;                                // 32-row tile
        const int ch = (nb_ >> 3) & 3;                          // 8-m chunk
        const int mm0 = nb_ & 7;                                // 0 or 4
#pragma unroll
        for (int cs = 0; cs < 8; ++cs) {
            int d = 16 * cs + l15;
            float bb = bias[d];
            u16x4 o;
#pragma unroll
            for (int j = 0; j < 4; ++j) o[j] = f2bf(acc[cs][j] + bb);
            size_t idx = ((size_t)(bb_ * 128 + pt)) * 4096 + ch * 1024 + d * 8 + mm0;
            *reinterpret_cast<u16x4*>(vs + idx) = o;
        }
    }
}

// ---------------- Kernel 2: fused masked flash attention (KV-split) ----------------
// grid 1024 x 128 threads (2 waves). Each block: one (batch, qtile, split),
// processes NTL=64 tiles of 32 kv rows. LDS 34 KB -> 4 blocks/CU (8 waves/CU).
__global__ __launch_bounds__(128, 2) void attn(
    const unsigned short* __restrict__ Q,   // [B*N,128] bf16, pre-scaled
    const unsigned short* __restrict__ K,   // [B*N,128] bf16
    const unsigned short* __restrict__ VS,  // tiled V (see proj)
    const int* __restrict__ adj,            // [B,N,N] i32
    float* __restrict__ opart,              // [2][NR][128] f32
    float* __restrict__ ml)                 // [2][NR][2] f32 (m, l)
{
    __shared__ unsigned short kA[KVB * 128], kB[KVB * 128];   // 8 KB each
    __shared__ unsigned short vA[4096], vB[4096];             // 8 KB each (tiled layout)
    __shared__ unsigned short p_lds[2 * 512];                 // per-wave 16x32 P tile

    const int tid = threadIdx.x;
    const int lane = tid & 63;
    const int w = tid >> 6;
    const int l15 = lane & 15;
    const int lhi = lane >> 4;

    // XCD swizzle: combo (b, sp) per XCD; 128 qtiles within
    const int flat = blockIdx.x;
    const int combo = flat & 7;
    const int qt = flat >> 3;
    const int b = combo >> 1;
    const int sp = combo & 1;
    const int q0 = qt * QB;
    const size_t bN = (size_t)b * NN;
    const size_t abase = (size_t)b * NN * NN;
    const int ptbase = sp * NTL;     // physical tile base for this split

    auto stage = [&](unsigned short* kb, unsigned short* vb, int pt) {
        const int m0 = pt * KVB;
#pragma unroll
        for (int i = 0; i < 4; ++i) {
            int slot = w * 4 + i;
            int row = slot * 4 + (lane >> 4);
            int pc = lane & 15;
            int lc = pc ^ (row & 7);
            gld_lds16(K + (bN + m0 + row) * ND + lc * 8, kb + slot * 512);
        }
        const unsigned short* vsrc = VS + ((size_t)(b * 128 + pt)) * 4096;
#pragma unroll
        for (int i = 0; i < 4; ++i) {
            int slot = w * 4 + i;
            gld_lds16(vsrc + slot * 512 + lane * 8, vb + slot * 512);
        }
    };
    auto adj_load = [&](int (&ar)[8], int pt) {
        const int m0 = pt * KVB;
#pragma unroll
        for (int ms = 0; ms < 2; ++ms)
#pragma unroll
            for (int j = 0; j < 4; ++j) {
                int r = 16 * w + 4 * lhi + j;
                int c = 16 * ms + l15;
                ar[ms * 4 + j] = adj[abase + (size_t)(q0 + r) * NN + m0 + c];
            }
    };

    int aregA[8], aregB[8];
    stage(kA, vA, ptbase);
    adj_load(aregA, ptbase);

    bf16x8 qf[4];
#pragma unroll
    for (int ks = 0; ks < 4; ++ks)
        qf[ks] = *reinterpret_cast<const bf16x8*>(Q + (bN + q0 + 16 * w + l15) * ND + ks * 32 + 8 * lhi);

    f32x4 acc_o[8];
#pragma unroll
    for (int i = 0; i < 8; ++i) acc_o[i] = f32x4{0.f, 0.f, 0.f, 0.f};
    float m_run[4], l_run[4];
#pragma unroll
    for (int j = 0; j < 4; ++j) { m_run[j] = -INFINITY; l_run[j] = 0.f; }

    auto body = [&](unsigned short* kc, unsigned short* vc, const int (&ac)[8],
                    unsigned short* kn, unsigned short* vn, int (&an)[8], int t) {
        int tn = (t + 1 < NTL) ? t + 1 : NTL - 1;
        stage(kn, vn, ptbase + tn);
        adj_load(an, ptbase + tn);
        asm volatile("s_waitcnt vmcnt(16)" ::: "memory");
        __builtin_amdgcn_s_barrier();
        __builtin_amdgcn_sched_barrier(0);

        // ---- S = Q K^T  (32 m-cols = 2 subtiles)
        f32x4 s[2];
#pragma unroll
        for (int ms = 0; ms < 2; ++ms) {
            s[ms] = f32x4{0.f, 0.f, 0.f, 0.f};
#pragma unroll
            for (int ks = 0; ks < 4; ++ks) {
                int mrow = 16 * ms + l15;
                bf16x8 bf = lds_read16(kc, (mrow * 256 + ks * 64 + lhi * 16) ^ ((mrow & 7) << 4));
                s[ms] = __builtin_amdgcn_mfma_f32_16x16x32_bf16(qf[ks], bf, s[ms], 0, 0, 0);
            }
        }
        // ---- mask
#pragma unroll
        for (int ms = 0; ms < 2; ++ms)
#pragma unroll
            for (int j = 0; j < 4; ++j)
                if (ac[ms * 4 + j] == 0) s[ms][j] = -9e15f;
        // ---- online softmax
        float mnew[4], corr[4];
#pragma unroll
        for (int j = 0; j < 4; ++j) {
            float mx = fmaxf(s[0][j], s[1][j]);
#pragma unroll
            for (int off = 1; off < 16; off <<= 1)
                mx = fmaxf(mx, __shfl_xor(mx, off, 64));
            mnew[j] = fmaxf(m_run[j], mx);
            corr[j] = __expf(m_run[j] - mnew[j]);
            m_run[j] = mnew[j];
        }
        float rsum[4] = {0.f, 0.f, 0.f, 0.f};
        unsigned short pb[2][4];
#pragma unroll
        for (int ms = 0; ms < 2; ++ms)
#pragma unroll
            for (int j = 0; j < 4; ++j) {
                float p = __expf(s[ms][j] - mnew[j]);
                rsum[j] += p;
                pb[ms][j] = f2bf(p);
            }
#pragma unroll
        for (int j = 0; j < 4; ++j) {
            float rs = rsum[j];
#pragma unroll
            for (int off = 1; off < 16; off <<= 1)
                rs += __shfl_xor(rs, off, 64);
            l_run[j] = l_run[j] * corr[j] + rs;
#pragma unroll
            for (int ds = 0; ds < 8; ++ds) acc_o[ds][j] *= corr[j];
        }
        // ---- P -> per-wave LDS tile [16 q][32 m], 64B rows, (r&7)<<4 swizzle
#pragma unroll
        for (int ms = 0; ms < 2; ++ms)
#pragma unroll
            for (int j = 0; j < 4; ++j) {
                int r = 4 * lhi + j;
                int c = 16 * ms + l15;
                int byte = w * 1024 + ((r * 64 + c * 2) ^ ((r & 7) << 4));
                *reinterpret_cast<unsigned short*>(reinterpret_cast<char*>(p_lds) + byte) = pb[ms][j];
            }
        // ---- PV: acc_o += P @ V   (single 32-k window)
        {
            bf16x8 pa = lds_read16(p_lds, w * 1024 + ((l15 * 64 + lhi * 16) ^ ((l15 & 7) << 4)));
#pragma unroll
            for (int ds = 0; ds < 8; ++ds) {
                int d = 16 * ds + l15;
                bf16x8 vbf = lds_read16(vc, lhi * 2048 + d * 16);
                acc_o[ds] = __builtin_amdgcn_mfma_f32_16x16x32_bf16(pa, vbf, acc_o[ds], 0, 0, 0);
            }
        }
        asm volatile("s_waitcnt lgkmcnt(0)" ::: "memory");
        __builtin_amdgcn_sched_barrier(0);
        __builtin_amdgcn_s_barrier();
        __builtin_amdgcn_sched_barrier(0);
    };

    for (int t = 0; t < NTL; t += 2) {
        body(kA, vA, aregA, kB, vB, aregB, t);
        body(kB, vB, aregB, kA, vA, aregA, t + 1);
    }

    // ---- epilogue: store partial O (unnormalized) + (m, l)
    float* op = opart + (size_t)sp * NR * ND;
#pragma unroll
    for (int ds = 0; ds < 8; ++ds) {
        int d = 16 * ds + l15;
#pragma unroll
        for (int j = 0; j < 4; ++j) {
            int row = q0 + 16 * w + 4 * lhi + j;
            op[(bN + row) * ND + d] = acc_o[ds][j];
        }
    }
    if (l15 == 0) {
#pragma unroll
        for (int j = 0; j < 4; ++j) {
            size_t gr = bN + q0 + 16 * w + 4 * lhi + j;
            float2 v2 = make_float2(m_run[j], l_run[j]);
            *reinterpret_cast<float2*>(ml + ((size_t)sp * NR + gr) * 2) = v2;
        }
    }
}

// ---------------- Kernel 3: merge the two KV-splits ----------------
__global__ __launch_bounds__(256) void merge_splits(
    const float* __restrict__ opart, const float* __restrict__ ml,
    float* __restrict__ out)
{
    int idx = blockIdx.x * 256 + threadIdx.x;   // 0 .. NR*32-1
    int row = idx >> 5;
    int d4 = (idx & 31) * 4;
    f32x4 o1 = *reinterpret_cast<const f32x4*>(opart + (size_t)row * ND + d4);
    f32x4 o2 = *reinterpret_cast<const f32x4*>(opart + ((size_t)NR + row) * ND + d4);
    float m1 = ml[(size_t)row * 2], l1 = ml[(size_t)row * 2 + 1];
    float m2 = ml[((size_t)NR + row) * 2], l2 = ml[((size_t)NR + row) * 2 + 1];
    float m = fmaxf(m1, m2);
    float w1 = __expf(m1 - m), w2 = __expf(m2 - m);
    float inv = 1.0f / (l1 * w1 + l2 * w2);
    f32x4 r;
#pragma unroll
    for (int j = 0; j < 4; ++j) r[j] = (o1[j] * w1 + o2[j] * w2) * inv;
    *reinterpret_cast<f32x4*>(out + (size_t)row * ND + d4) = r;
}

extern "C" void kernel_launch(void* const* d_in, const int* in_sizes, int n_in,
                              void* d_out, int out_size, void* d_ws, size_t ws_size,
                              hipStream_t stream) {
    const float* h  = (const float*)d_in[0];
    const int* adj  = (const int*)d_in[1];
    const float* Wq = (const float*)d_in[2];
    const float* bq = (const float*)d_in[3];
    const float* Wk = (const float*)d_in[4];
    const float* bk = (const float*)d_in[5];
    const float* Wv = (const float*)d_in[6];
    const float* bv = (const float*)d_in[7];
    float* out = (float*)d_out;

    unsigned short* qws = (unsigned short*)d_ws;
    unsigned short* kws = qws + (size_t)NB * NN * ND;
    unsigned short* vsws = kws + (size_t)NB * NN * ND;
    float* opart = (float*)(vsws + (size_t)NB * NN * ND);
    float* mlws  = opart + (size_t)NSPLIT * NR * ND;

    const float qscale = 0.08838834764831845f;  // 1/sqrt(128)

    qkv_proj<<<dim3(NB * NN / 64, 3), 256, 0, stream>>>(
        h, Wq, bq, Wk, bk, Wv, bv, qws, kws, vsws, qscale);
    attn<<<dim3(NB * (NN / QB) * NSPLIT / 1), 128, 0, stream>>>(
        qws, kws, vsws, adj, opart, mlws);
    merge_splits<<<dim3(NR * 32 / 256), 256, 0, stream>>>(opart, mlws, out);
}